// Round 1
// baseline (279.699 us; speedup 1.0000x reference)
//
#include <hip/hip_runtime.h>
#include <stdint.h>

#define N_TOK 64
#define K_DIM 4096
#define N_OUT 11008
#define LUT_N 256

typedef __attribute__((ext_vector_type(4))) float  floatx4;
typedef __attribute__((ext_vector_type(8))) __bf16 bf16x8;

__device__ __forceinline__ unsigned bf16_rne(float f) {
  unsigned u = __builtin_bit_cast(unsigned, f);
  return (u + 0x7fffu + ((u >> 16) & 1u)) >> 16;  // round-nearest-even to bf16
}

// ---- pre-kernel: x fp32 -> bf16 into workspace ----
__global__ __launch_bounds__(256) void xcvt_kernel(const float* __restrict__ x,
                                                   unsigned short* __restrict__ xb) {
  int i = (blockIdx.x * 256 + threadIdx.x) * 4;
  float4 v = *(const float4*)(x + i);
  ushort4 o;
  o.x = (unsigned short)bf16_rne(v.x);
  o.y = (unsigned short)bf16_rne(v.y);
  o.z = (unsigned short)bf16_rne(v.z);
  o.w = (unsigned short)bf16_rne(v.w);
  *(ushort4*)(xb + i) = o;
}

// ---- main kernel ----
// block: 16 output features, 256 threads = 4 waves; wave w owns K in [w*1024,(w+1)*1024)
// MFMA 16x16x32 bf16:  A = x (m=token), B = dequant W^T (n=feature)
// A-frag: A[m=lane&15][k=quad*8+j]   B-frag: B[k=quad*8+j][n=lane&15]
// C/D:    row(token)=quad*4+reg, col(feature)=lane&15
template <bool XB>
__global__ __launch_bounds__(256, 3) void ghost_kernel(
    const float* __restrict__ x, const int* __restrict__ gidx,
    const float* __restrict__ lut, const float* __restrict__ scale,
    const unsigned short* __restrict__ xb, float* __restrict__ out) {
  __shared__ unsigned lut_lds[LUT_N * 16];  // 16 bank-strided copies, bf16 in low16
  __shared__ floatx4 red[4][4][64];         // 16 KB cross-wave reduction buffer

  const int tid = threadIdx.x;
  {  // build replicated LUT: copy c at dword [v*16+c] -> lane uses copy lane&15
    unsigned hb = bf16_rne(lut[tid]);
#pragma unroll
    for (int c = 0; c < 16; ++c) lut_lds[tid * 16 + c] = hb;
  }
  __syncthreads();

  const int w    = tid >> 6;
  const int lane = tid & 63;
  const int m15  = lane & 15;  // feature-in-strip (B,n / C col) and token-in-tile (A,m)
  const int q    = lane >> 4;  // quad
  const int o    = blockIdx.x * 16 + m15;
  const int kw0  = w * 1024;

  const int* idxp = gidx + (size_t)o * K_DIM + kw0 + q * 8;

  floatx4 acc[4];
#pragma unroll
  for (int tt = 0; tt < 4; ++tt) acc[tt] = (floatx4){0.f, 0.f, 0.f, 0.f};

  int4 buf[2][4];  // [parity][2*step+half] : 8 idx/lane per K-step(32), 2 steps/window(64)
#pragma unroll
  for (int s = 0; s < 2; ++s) {
    buf[0][2 * s + 0] = *(const int4*)(idxp + 32 * s);
    buf[0][2 * s + 1] = *(const int4*)(idxp + 32 * s + 4);
  }

#pragma unroll 2
  for (int win = 0; win < 16; ++win) {
    const int cu = win & 1, nx = cu ^ 1;
    if (win < 15) {  // prefetch next 64-K window (stays in flight through this window)
      const int* p = idxp + (win + 1) * 64;
#pragma unroll
      for (int s = 0; s < 2; ++s) {
        buf[nx][2 * s + 0] = *(const int4*)(p + 32 * s);
        buf[nx][2 * s + 1] = *(const int4*)(p + 32 * s + 4);
      }
    }

    // A-fragment loads (x), 4 token tiles x 2 K-steps
    uint4  axb[4][2];
    float4 axf[4][2][2];
#pragma unroll
    for (int tt = 0; tt < 4; ++tt)
#pragma unroll
      for (int s = 0; s < 2; ++s) {
        const int e = (tt * 16 + m15) * K_DIM + kw0 + win * 64 + 32 * s + 8 * q;
        if constexpr (XB) {
          axb[tt][s] = *(const uint4*)(xb + e);
        } else {
          axf[tt][s][0] = *(const float4*)(x + e);
          axf[tt][s][1] = *(const float4*)(x + e + 4);
        }
      }

#pragma unroll
    for (int s = 0; s < 2; ++s) {
      const int4 i0 = buf[cu][2 * s + 0];
      const int4 i1 = buf[cu][2 * s + 1];
      // LUT gathers: copy = lane&15 -> bank = (v*16+m15)&31, <=2 lanes/bank typical
      unsigned g0 = lut_lds[i0.x * 16 + m15];
      unsigned g1 = lut_lds[i0.y * 16 + m15];
      unsigned g2 = lut_lds[i0.z * 16 + m15];
      unsigned g3 = lut_lds[i0.w * 16 + m15];
      unsigned g4 = lut_lds[i1.x * 16 + m15];
      unsigned g5 = lut_lds[i1.y * 16 + m15];
      unsigned g6 = lut_lds[i1.z * 16 + m15];
      unsigned g7 = lut_lds[i1.w * 16 + m15];
      uint4 bi;
      bi.x = __builtin_amdgcn_perm(g1, g0, 0x05040100u);  // [bf16(k0)|bf16(k1)<<16]
      bi.y = __builtin_amdgcn_perm(g3, g2, 0x05040100u);
      bi.z = __builtin_amdgcn_perm(g5, g4, 0x05040100u);
      bi.w = __builtin_amdgcn_perm(g7, g6, 0x05040100u);
      bf16x8 bfrag = __builtin_bit_cast(bf16x8, bi);

#pragma unroll
      for (int tt = 0; tt < 4; ++tt) {
        bf16x8 afrag;
        if constexpr (XB) {
          afrag = __builtin_bit_cast(bf16x8, axb[tt][s]);
        } else {
          const float4 lo = axf[tt][s][0], hi = axf[tt][s][1];
          uint4 ai;
          ai.x = __builtin_amdgcn_perm(__builtin_bit_cast(unsigned, lo.y),
                                       __builtin_bit_cast(unsigned, lo.x), 0x07060302u);
          ai.y = __builtin_amdgcn_perm(__builtin_bit_cast(unsigned, lo.w),
                                       __builtin_bit_cast(unsigned, lo.z), 0x07060302u);
          ai.z = __builtin_amdgcn_perm(__builtin_bit_cast(unsigned, hi.y),
                                       __builtin_bit_cast(unsigned, hi.x), 0x07060302u);
          ai.w = __builtin_amdgcn_perm(__builtin_bit_cast(unsigned, hi.w),
                                       __builtin_bit_cast(unsigned, hi.z), 0x07060302u);
          afrag = __builtin_bit_cast(bf16x8, ai);
        }
        acc[tt] = __builtin_amdgcn_mfma_f32_16x16x32_bf16(afrag, bfrag, acc[tt], 0, 0, 0);
      }
    }
  }

  // ---- cross-wave K reduction + scale + store ----
  __syncthreads();
#pragma unroll
  for (int tt = 0; tt < 4; ++tt) red[w][tt][lane] = acc[tt];
  __syncthreads();
  {
    floatx4 r = red[0][w][lane];
    r += red[1][w][lane];
    r += red[2][w][lane];
    r += red[3][w][lane];
    const float sc = scale[blockIdx.x * 16 + m15];
    r *= sc;
#pragma unroll
    for (int i = 0; i < 4; ++i)
      out[(size_t)(16 * w + q * 4 + i) * N_OUT + blockIdx.x * 16 + m15] = r[i];
  }
}

extern "C" void kernel_launch(void* const* d_in, const int* in_sizes, int n_in,
                              void* d_out, int out_size, void* d_ws, size_t ws_size,
                              hipStream_t stream) {
  const float* x   = (const float*)d_in[0];
  const int*   gi  = (const int*)d_in[1];
  const float* lut = (const float*)d_in[2];
  const float* sc  = (const float*)d_in[3];
  float*       out = (float*)d_out;

  const size_t xb_bytes = (size_t)N_TOK * K_DIM * sizeof(unsigned short);
  if (ws_size >= xb_bytes) {
    unsigned short* xb = (unsigned short*)d_ws;
    xcvt_kernel<<<(N_TOK * K_DIM) / (256 * 4), 256, 0, stream>>>(x, xb);
    ghost_kernel<true><<<N_OUT / 16, 256, 0, stream>>>(x, gi, lut, sc, xb, out);
  } else {
    ghost_kernel<false><<<N_OUT / 16, 256, 0, stream>>>(x, gi, lut, sc, nullptr, out);
  }
}

// Round 2
// 273.648 us; speedup vs baseline: 1.0221x; 1.0221x over previous
//
#include <hip/hip_runtime.h>
#include <stdint.h>

#define N_TOK 64
#define K_DIM 4096
#define N_OUT 11008
#define LUT_N 256

typedef __attribute__((ext_vector_type(4))) float  floatx4;
typedef __attribute__((ext_vector_type(8))) __bf16 bf16x8;

__device__ __forceinline__ unsigned bf16_rne(float f) {
  unsigned u = __builtin_bit_cast(unsigned, f);
  return (u + 0x7fffu + ((u >> 16) & 1u)) >> 16;  // round-nearest-even to bf16
}

// ---- pre-kernel: pack x (fp32 [64][4096]) into A-fragment-ordered bf16 ----
// chunk c = (w*32 + st)*4 + tt   (st = K-step of 32 within wave-w's K range)
// within chunk: lane = q*16+m15 holds 8 bf16 (16 B), element j =
//   x[(tt*16+m15)*4096 + w*1024 + st*32 + q*8 + j]
// => ghost kernel's A-load is lane-contiguous dwordx4 (perfectly coalesced)
__global__ __launch_bounds__(256) void xpack_kernel(const float* __restrict__ x,
                                                    uint32_t* __restrict__ xp) {
  const int t = blockIdx.x * 256 + threadIdx.x;  // [0, 32768)
  const int lane = t & 63, c = t >> 6;
  const int m15 = lane & 15, q = lane >> 4;
  const int tt = c & 3, st = (c >> 2) & 31, w = c >> 7;
  const int src = (tt * 16 + m15) * K_DIM + w * 1024 + st * 32 + q * 8;
  float4 a = *(const float4*)(x + src);
  float4 b = *(const float4*)(x + src + 4);
  uint4 o;
  o.x = bf16_rne(a.x) | (bf16_rne(a.y) << 16);
  o.y = bf16_rne(a.z) | (bf16_rne(a.w) << 16);
  o.z = bf16_rne(b.x) | (bf16_rne(b.y) << 16);
  o.w = bf16_rne(b.z) | (bf16_rne(b.w) << 16);
  *(uint4*)(xp + (size_t)t * 4) = o;
}

// ---- main kernel ----
// block: 16 output features, 4 waves; wave w owns K in [w*1024,(w+1)*1024)
// 32 K-steps of 32; BOTH idx and A streams pipelined at depth 4 so no
// s_waitcnt drains the in-flight queue below ~18 loads (6 KB/wave HBM idx).
// MFMA 16x16x32 bf16: A-frag A[m=lane&15][k=q*8+j], B-frag B[k=q*8+j][n=lane&15]
// C/D: row(token)=q*4+reg, col(feature)=lane&15
__global__ __launch_bounds__(256, 3) void ghost_kernel(
    const int* __restrict__ gidx, const float* __restrict__ lut,
    const float* __restrict__ scale, const uint32_t* __restrict__ xp,
    float* __restrict__ out) {
  __shared__ unsigned lut_lds[LUT_N * 16];  // 16 bank-strided copies, bf16 in low16
  __shared__ floatx4 red[4][4][64];         // 16 KB cross-wave reduction buffer

  const int tid = threadIdx.x;
  {  // replicated LUT: copy c at dword [v*16+c]; lane uses copy lane&15
    unsigned hb = bf16_rne(lut[tid]);
#pragma unroll
    for (int c = 0; c < 16; ++c) lut_lds[tid * 16 + c] = hb;
  }
  __syncthreads();

  const int w = tid >> 6, lane = tid & 63;
  const int m15 = lane & 15, q = lane >> 4;
  const int o = blockIdx.x * 16 + m15;

  // idx: per step st, lane reads 8 ints at row o, col w*1024 + st*32 + q*8
  const int* idxp = gidx + (size_t)o * K_DIM + w * 1024 + q * 8;
  // A: chunk (w*32+st)*4+tt, 64 uint4 per chunk, + lane
  const uint4* ap = (const uint4*)xp + (size_t)w * 32 * 4 * 64 + lane;

  floatx4 acc[4];
#pragma unroll
  for (int tt = 0; tt < 4; ++tt) acc[tt] = (floatx4){0.f, 0.f, 0.f, 0.f};

  int4  ib[4][2];  // idx pipeline, depth 4
  uint4 ab[4][4];  // A pipeline, depth 4 (4 token-tiles per step)
#pragma unroll
  for (int p = 0; p < 4; ++p) {
    ib[p][0] = *(const int4*)(idxp + p * 32);
    ib[p][1] = *(const int4*)(idxp + p * 32 + 4);
#pragma unroll
    for (int tt = 0; tt < 4; ++tt) ab[p][tt] = ap[(p * 4 + tt) * 64];
  }

#pragma unroll 4
  for (int st = 0; st < 32; ++st) {
    const int p = st & 3;
    // consume-side copies (registers; compiler renames)
    const int4 i0 = ib[p][0], i1 = ib[p][1];
    uint4 a0 = ab[p][0], a1 = ab[p][1], a2 = ab[p][2], a3 = ab[p][3];
    // prefetch step st+4 into slot p (issued before any wait on old data)
    if (st < 28) {
      ib[p][0] = *(const int4*)(idxp + (st + 4) * 32);
      ib[p][1] = *(const int4*)(idxp + (st + 4) * 32 + 4);
#pragma unroll
      for (int tt = 0; tt < 4; ++tt) ab[p][tt] = ap[((st + 4) * 4 + tt) * 64];
    }

    // LUT gathers: dword addr v*16 + (lane&15) -> bank ((v&1)*16+m15)&31,
    // expected <=2 lanes/bank (free per m136)
    unsigned g0 = lut_lds[i0.x * 16 + m15];
    unsigned g1 = lut_lds[i0.y * 16 + m15];
    unsigned g2 = lut_lds[i0.z * 16 + m15];
    unsigned g3 = lut_lds[i0.w * 16 + m15];
    unsigned g4 = lut_lds[i1.x * 16 + m15];
    unsigned g5 = lut_lds[i1.y * 16 + m15];
    unsigned g6 = lut_lds[i1.z * 16 + m15];
    unsigned g7 = lut_lds[i1.w * 16 + m15];
    uint4 bi;
    bi.x = __builtin_amdgcn_perm(g1, g0, 0x05040100u);  // [bf16(k0)|bf16(k1)<<16]
    bi.y = __builtin_amdgcn_perm(g3, g2, 0x05040100u);
    bi.z = __builtin_amdgcn_perm(g5, g4, 0x05040100u);
    bi.w = __builtin_amdgcn_perm(g7, g6, 0x05040100u);
    const bf16x8 bfrag = __builtin_bit_cast(bf16x8, bi);

    acc[0] = __builtin_amdgcn_mfma_f32_16x16x32_bf16(
        __builtin_bit_cast(bf16x8, a0), bfrag, acc[0], 0, 0, 0);
    acc[1] = __builtin_amdgcn_mfma_f32_16x16x32_bf16(
        __builtin_bit_cast(bf16x8, a1), bfrag, acc[1], 0, 0, 0);
    acc[2] = __builtin_amdgcn_mfma_f32_16x16x32_bf16(
        __builtin_bit_cast(bf16x8, a2), bfrag, acc[2], 0, 0, 0);
    acc[3] = __builtin_amdgcn_mfma_f32_16x16x32_bf16(
        __builtin_bit_cast(bf16x8, a3), bfrag, acc[3], 0, 0, 0);
  }

  // ---- cross-wave K reduction + scale + store ----
  __syncthreads();
#pragma unroll
  for (int tt = 0; tt < 4; ++tt) red[w][tt][lane] = acc[tt];
  __syncthreads();
  {
    floatx4 r = red[0][w][lane];
    r += red[1][w][lane];
    r += red[2][w][lane];
    r += red[3][w][lane];
    const float sc = scale[blockIdx.x * 16 + m15];
    r *= sc;
#pragma unroll
    for (int i = 0; i < 4; ++i)
      out[(size_t)(16 * w + q * 4 + i) * N_OUT + blockIdx.x * 16 + m15] = r[i];
  }
}

extern "C" void kernel_launch(void* const* d_in, const int* in_sizes, int n_in,
                              void* d_out, int out_size, void* d_ws, size_t ws_size,
                              hipStream_t stream) {
  const float* x   = (const float*)d_in[0];
  const int*   gi  = (const int*)d_in[1];
  const float* lut = (const float*)d_in[2];
  const float* sc  = (const float*)d_in[3];
  float*       out = (float*)d_out;

  uint32_t* xp = (uint32_t*)d_ws;  // 512 KB packed-A region
  xpack_kernel<<<(N_TOK * K_DIM / 8) / 256, 256, 0, stream>>>(x, xp);
  ghost_kernel<<<N_OUT / 16, 256, 0, stream>>>(gi, lut, sc, xp, out);
}

// Round 3
// 252.861 us; speedup vs baseline: 1.1061x; 1.0822x over previous
//
#include <hip/hip_runtime.h>
#include <stdint.h>

#define N_TOK 64
#define K_DIM 4096
#define N_OUT 11008
#define LUT_N 256
#define WIN 256      // K-columns per staged window
#define ROWPAD 260   // dwords per window row: 256 + 4 pad (keeps 16B align, breaks bank stride)

typedef __attribute__((ext_vector_type(4))) float  floatx4;
typedef __attribute__((ext_vector_type(8))) __bf16 bf16x8;

__device__ __forceinline__ unsigned bf16_rne(float f) {
  unsigned u = __builtin_bit_cast(unsigned, f);
  return (u + 0x7fffu + ((u >> 16) & 1u)) >> 16;  // round-nearest-even to bf16
}

// ---- pre-kernel: pack x (fp32 [64][4096]) into A-fragment-ordered bf16 ----
// chunk c = kstep*4 + tt, kstep in [0,128); lane (q,m15) holds 8 bf16:
//   x[(tt*16+m15)*4096 + kstep*32 + q*8 + j]
__global__ __launch_bounds__(256) void xpack_kernel(const float* __restrict__ x,
                                                    uint32_t* __restrict__ xp) {
  const int t = blockIdx.x * 256 + threadIdx.x;  // [0, 32768)
  const int lane = t & 63, c = t >> 6;
  const int m15 = lane & 15, q = lane >> 4;
  const int tt = c & 3, kstep = c >> 2;
  const int src = (tt * 16 + m15) * K_DIM + kstep * 32 + q * 8;
  float4 a = *(const float4*)(x + src);
  float4 b = *(const float4*)(x + src + 4);
  uint4 o;
  o.x = bf16_rne(a.x) | (bf16_rne(a.y) << 16);
  o.y = bf16_rne(a.z) | (bf16_rne(a.w) << 16);
  o.z = bf16_rne(b.x) | (bf16_rne(b.y) << 16);
  o.w = bf16_rne(b.z) | (bf16_rne(b.w) << 16);
  *(uint4*)(xp + (size_t)t * 4) = o;
}

// ---- main kernel ----
// Block = 16 output features. All 4 waves share a K-window of 256 cols staged
// in LDS via global_load_lds in 1-KB-per-row bursts (DRAM-page friendly).
// Within a window, wave w computes cols [w*64,(w+1)*64) = 2 MFMA K-steps.
// MFMA 16x16x32 bf16: A[m=lane&15][k=q*8+j], B[k=q*8+j][n=lane&15];
// C/D: row(token)=q*4+reg, col(feature)=lane&15.
__global__ __launch_bounds__(256, 3) void ghost_kernel(
    const int* __restrict__ gidx, const float* __restrict__ lut,
    const float* __restrict__ scale, const uint32_t* __restrict__ xp,
    float* __restrict__ out) {
  __shared__ uint32_t lut_lds[LUT_N * 16];   // 16 bank-strided LUT copies (16 KB)
  __shared__ uint32_t win[2][16 * ROWPAD];   // double-buffered idx windows (33 KB)

  const int tid = threadIdx.x;
  const int w = tid >> 6, lane = tid & 63;
  const int m15 = lane & 15, q = lane >> 4;
  const int blk = blockIdx.x;

  const int* grow = gidx + (size_t)blk * 16 * K_DIM;

  // stage window n into win[n&1]: wave w loads rows 4w..4w+3, 1 KB contiguous each
  auto load_win = [&](int n) {
    uint32_t* dst = &win[n & 1][0];
#pragma unroll
    for (int j = 0; j < 4; ++j) {
      const int r = 4 * w + j;
      const int* g = grow + (size_t)r * K_DIM + n * WIN + lane * 4;
      __builtin_amdgcn_global_load_lds(
          (const __attribute__((address_space(1))) void*)g,
          (__attribute__((address_space(3))) void*)(dst + r * ROWPAD), 16, 0, 0);
    }
  };

  load_win(0);  // issue first window before anything else (longest latency)

  {  // replicated LUT: copy c at dword [v*16+c]; lane uses copy lane&15
    unsigned hb = bf16_rne(lut[tid]);
#pragma unroll
    for (int c = 0; c < 16; ++c) lut_lds[tid * 16 + c] = hb;
  }

  floatx4 acc[4];
#pragma unroll
  for (int tt = 0; tt < 4; ++tt) acc[tt] = (floatx4){0.f, 0.f, 0.f, 0.f};

  const uint4* ap = (const uint4*)xp;

  for (int n = 0; n < 16; ++n) {
    __syncthreads();  // window n staged & visible; everyone done with buf (n+1)&1
    if (n < 15) load_win(n + 1);  // 1-KB bursts stay in flight through compute n
    const uint32_t* wb = &win[n & 1][0];
    const int kb = n * 8 + w * 2;  // global K-step base for this wave

#pragma unroll
    for (int s = 0; s < 2; ++s) {
      // A fragments (xp is L2-resident; latency hidden by LDS work below)
      uint4 a0 = ap[(size_t)((kb + s) * 4 + 0) * 64 + lane];
      uint4 a1 = ap[(size_t)((kb + s) * 4 + 1) * 64 + lane];
      uint4 a2 = ap[(size_t)((kb + s) * 4 + 2) * 64 + lane];
      uint4 a3 = ap[(size_t)((kb + s) * 4 + 3) * 64 + lane];

      // idx readback: 2x ds_read_b128, bank-minimal with ROWPAD=260
      const uint32_t* ip = wb + m15 * ROWPAD + w * 64 + s * 32 + q * 8;
      const uint4 iv0 = *(const uint4*)ip;
      const uint4 iv1 = *(const uint4*)(ip + 4);

      // LUT gathers: dword addr v*16 + m15 -> <=2 lanes/bank typical (free)
      unsigned g0 = lut_lds[iv0.x * 16 + m15];
      unsigned g1 = lut_lds[iv0.y * 16 + m15];
      unsigned g2 = lut_lds[iv0.z * 16 + m15];
      unsigned g3 = lut_lds[iv0.w * 16 + m15];
      unsigned g4 = lut_lds[iv1.x * 16 + m15];
      unsigned g5 = lut_lds[iv1.y * 16 + m15];
      unsigned g6 = lut_lds[iv1.z * 16 + m15];
      unsigned g7 = lut_lds[iv1.w * 16 + m15];
      uint4 bi;
      bi.x = __builtin_amdgcn_perm(g1, g0, 0x05040100u);  // [bf16(k0)|bf16(k1)<<16]
      bi.y = __builtin_amdgcn_perm(g3, g2, 0x05040100u);
      bi.z = __builtin_amdgcn_perm(g5, g4, 0x05040100u);
      bi.w = __builtin_amdgcn_perm(g7, g6, 0x05040100u);
      const bf16x8 bfrag = __builtin_bit_cast(bf16x8, bi);

      acc[0] = __builtin_amdgcn_mfma_f32_16x16x32_bf16(
          __builtin_bit_cast(bf16x8, a0), bfrag, acc[0], 0, 0, 0);
      acc[1] = __builtin_amdgcn_mfma_f32_16x16x32_bf16(
          __builtin_bit_cast(bf16x8, a1), bfrag, acc[1], 0, 0, 0);
      acc[2] = __builtin_amdgcn_mfma_f32_16x16x32_bf16(
          __builtin_bit_cast(bf16x8, a2), bfrag, acc[2], 0, 0, 0);
      acc[3] = __builtin_amdgcn_mfma_f32_16x16x32_bf16(
          __builtin_bit_cast(bf16x8, a3), bfrag, acc[3], 0, 0, 0);
    }
  }

  // ---- cross-wave K reduction (reuse win[0] as scratch) + scale + store ----
  __syncthreads();
  floatx4* red = (floatx4*)&win[0][0];  // 16 KB of the 16.6 KB buffer
#pragma unroll
  for (int tt = 0; tt < 4; ++tt) red[(w * 4 + tt) * 64 + lane] = acc[tt];
  __syncthreads();
  {
    floatx4 r = red[(0 * 4 + w) * 64 + lane];
    r += red[(1 * 4 + w) * 64 + lane];
    r += red[(2 * 4 + w) * 64 + lane];
    r += red[(3 * 4 + w) * 64 + lane];
    const float sc = scale[blk * 16 + m15];
    r *= sc;
#pragma unroll
    for (int i = 0; i < 4; ++i)
      out[(size_t)(16 * w + q * 4 + i) * N_OUT + blk * 16 + m15] = r[i];
  }
}

extern "C" void kernel_launch(void* const* d_in, const int* in_sizes, int n_in,
                              void* d_out, int out_size, void* d_ws, size_t ws_size,
                              hipStream_t stream) {
  const float* x   = (const float*)d_in[0];
  const int*   gi  = (const int*)d_in[1];
  const float* lut = (const float*)d_in[2];
  const float* sc  = (const float*)d_in[3];
  float*       out = (float*)d_out;

  uint32_t* xp = (uint32_t*)d_ws;  // 512 KB packed-A region
  xpack_kernel<<<(N_TOK * K_DIM / 8) / 256, 256, 0, stream>>>(x, xp);
  ghost_kernel<<<N_OUT / 16, 256, 0, stream>>>(gi, lut, sc, xp, out);
}